// Round 1
// baseline (585.254 us; speedup 1.0000x reference)
//
#include <hip/hip_runtime.h>
#include <hip/hip_bf16.h>

// Problem dims (fixed by reference):
//   x:  [B=16, c_in=64, T=64, N=512] fp32
//   La: [B=16, N=512, N=512] fp32
//   W:  [c_out=64, K*c_in=192] fp32
//   out:[B, 64, T, N] fp32
// Math: out[b,o,t,q] = sum_{c,k} W[o, c*3+k] * z_k[b,c,t,q]
//   z0 = x ; z1 = X @ La^T (rows ct, reduce n) ; z2 = 2*(z1 @ La^T) - x
// (Chebyshev recurrence applied to features instead of forming La^2.)

#define B_   16
#define CIN  64
#define T_   64
#define N_   512
#define M_   4096   // CIN*T_ rows per batch
#define KDIM 512
#define COUT 64

typedef __bf16 bf16x8 __attribute__((ext_vector_type(8)));
typedef float  floatx4 __attribute__((ext_vector_type(4)));

__device__ __forceinline__ float bf2f(unsigned short u) {
    unsigned int v = ((unsigned int)u) << 16;
    return __builtin_bit_cast(float, v);
}
__device__ __forceinline__ unsigned short f2bf(float f) {
    unsigned int u = __builtin_bit_cast(unsigned int, f);
    unsigned int lsb = (u >> 16) & 1u;
    u += 0x7fffu + lsb;           // round-to-nearest-even
    return (unsigned short)(u >> 16);
}

// ---- K0a/K0b: fp32 -> bf16 convert, 8 elems/thread ----
__global__ __launch_bounds__(256) void cvt_f32_bf16(
    const float* __restrict__ src, unsigned short* __restrict__ dst, int n)
{
    int i = (blockIdx.x * 256 + threadIdx.x) * 8;
    if (i + 8 <= n) {
        float4 a = *(const float4*)(src + i);
        float4 b = *(const float4*)(src + i + 4);
        union { unsigned short s[8]; uint4 u; } o;
        o.s[0] = f2bf(a.x); o.s[1] = f2bf(a.y); o.s[2] = f2bf(a.z); o.s[3] = f2bf(a.w);
        o.s[4] = f2bf(b.x); o.s[5] = f2bf(b.y); o.s[6] = f2bf(b.z); o.s[7] = f2bf(b.w);
        *(uint4*)(dst + i) = o.u;
    }
}

// ---- K0c: repack W[o][c*3+k] -> Wp[k*64+c][o] (fp32, 192x64) ----
__global__ __launch_bounds__(256) void pack_w(
    const float* __restrict__ W, float* __restrict__ Wp)
{
    for (int idx = threadIdx.x + blockIdx.x * 256; idx < 192 * 64; idx += gridDim.x * 256) {
        int j = idx >> 6, o = idx & 63;
        int c = j & 63,  k = j >> 6;
        Wp[idx] = W[o * 192 + c * 3 + k];
    }
}

// ---- K1/K2: batched bf16 NT-GEMM  C[m][q] = sum_n A[m][n]*Bm[q][n] ----
// mode 0: C = acc ; mode 1: C = 2*acc - X  (X same layout as C)
#define BM 128
#define BN 128
#define BK 32
#define LDSP 40   // padded LDS pitch in bf16 elems (80 B rows; (r,r+8) 2-way only)

__global__ __launch_bounds__(256) void gemm_bt(
    const unsigned short* __restrict__ A,
    const unsigned short* __restrict__ Bm,
    unsigned short* __restrict__ C,
    const unsigned short* __restrict__ X,
    int mode)
{
    int batch = blockIdx.z;
    A  += (size_t)batch * M_ * KDIM;
    Bm += (size_t)batch * N_ * KDIM;
    C  += (size_t)batch * M_ * N_;
    X  += (size_t)batch * M_ * N_;
    int m0 = blockIdx.y * BM;
    int n0 = blockIdx.x * BN;

    __shared__ __align__(16) unsigned short As[BM * LDSP];
    __shared__ __align__(16) unsigned short Bs[BN * LDSP];

    int tid  = threadIdx.x;
    int lane = tid & 63;
    int wave = tid >> 6;
    int wm   = (wave >> 1) * 64;
    int wn   = (wave & 1) * 64;
    int l15  = lane & 15;
    int quad = lane >> 4;

    floatx4 acc[4][4];
#pragma unroll
    for (int i = 0; i < 4; i++)
#pragma unroll
        for (int j = 0; j < 4; j++) acc[i][j] = (floatx4)0.0f;

    int srow = tid >> 2;   // 0..63
    int skc  = tid & 3;    // 0..3 (16B chunk within 64B of BK row)

    for (int k0 = 0; k0 < KDIM; k0 += BK) {
        __syncthreads();
        {
            const uint4* ga1 = (const uint4*)(A  + (size_t)(m0 + srow)      * KDIM + k0) + skc;
            const uint4* ga2 = (const uint4*)(A  + (size_t)(m0 + srow + 64) * KDIM + k0) + skc;
            const uint4* gb1 = (const uint4*)(Bm + (size_t)(n0 + srow)      * KDIM + k0) + skc;
            const uint4* gb2 = (const uint4*)(Bm + (size_t)(n0 + srow + 64) * KDIM + k0) + skc;
            *(uint4*)(&As[(srow)      * LDSP + skc * 8]) = *ga1;
            *(uint4*)(&As[(srow + 64) * LDSP + skc * 8]) = *ga2;
            *(uint4*)(&Bs[(srow)      * LDSP + skc * 8]) = *gb1;
            *(uint4*)(&Bs[(srow + 64) * LDSP + skc * 8]) = *gb2;
        }
        __syncthreads();

        bf16x8 af[4], bf[4];
#pragma unroll
        for (int im = 0; im < 4; im++)
            af[im] = __builtin_bit_cast(bf16x8,
                *(const uint4*)(&As[(wm + im * 16 + l15) * LDSP + quad * 8]));
#pragma unroll
        for (int jn = 0; jn < 4; jn++)
            bf[jn] = __builtin_bit_cast(bf16x8,
                *(const uint4*)(&Bs[(wn + jn * 16 + l15) * LDSP + quad * 8]));
#pragma unroll
        for (int im = 0; im < 4; im++)
#pragma unroll
            for (int jn = 0; jn < 4; jn++)
                acc[im][jn] = __builtin_amdgcn_mfma_f32_16x16x32_bf16(
                    af[im], bf[jn], acc[im][jn], 0, 0, 0);
    }

    // epilogue: C/D layout col = lane&15, row = quad*4 + reg   [m89/m91 verified]
#pragma unroll
    for (int im = 0; im < 4; im++)
#pragma unroll
        for (int jn = 0; jn < 4; jn++) {
            int c = n0 + wn + jn * 16 + l15;
#pragma unroll
            for (int r = 0; r < 4; r++) {
                int m = m0 + wm + im * 16 + quad * 4 + r;
                size_t idx = (size_t)m * N_ + c;
                float v = acc[im][jn][r];
                if (mode) v = 2.0f * v - bf2f(X[idx]);
                C[idx] = f2bf(v);
            }
        }
}

// ---- K3: projection out[b,o,t,q] = sum_j Wp[j][o]*D_j[b,t,q] ----
// Each thread: 16 o (o-group) x 4 q (q stride 64). W fp32 in LDS (48KB).
__global__ __launch_bounds__(256) void proj(
    const unsigned short* __restrict__ xb,
    const unsigned short* __restrict__ z1b,
    const unsigned short* __restrict__ z2b,
    const float* __restrict__ Wp,
    float* __restrict__ out)
{
    __shared__ float Wl[192 * 64];
    for (int i = threadIdx.x; i < 192 * 64; i += 256) Wl[i] = Wp[i];
    __syncthreads();

    int b  = blockIdx.z;
    int t  = blockIdx.y;
    int q0 = blockIdx.x * 256;
    int qb = threadIdx.x & 63;
    int og = threadIdx.x >> 6;      // wave-uniform
    int obase = og * 16;

    size_t base0 = (size_t)b * ((size_t)M_ * N_) + (size_t)t * N_ + q0 + qb;
    const unsigned short* ptrs[3] = { xb + base0, z1b + base0, z2b + base0 };

    float acc[4][16];
#pragma unroll
    for (int s = 0; s < 4; s++)
#pragma unroll
        for (int i = 0; i < 16; i++) acc[s][i] = 0.0f;

    for (int k = 0; k < 3; k++) {
        const unsigned short* P = ptrs[k];
#pragma unroll 2
        for (int c = 0; c < 64; c++) {
            float d0 = bf2f(P[(size_t)c * 32768 + 0]);
            float d1 = bf2f(P[(size_t)c * 32768 + 64]);
            float d2 = bf2f(P[(size_t)c * 32768 + 128]);
            float d3 = bf2f(P[(size_t)c * 32768 + 192]);
            const float4* wrow = (const float4*)(&Wl[(k * 64 + c) * 64 + obase]);
            float4 wa = wrow[0], wb = wrow[1], wc = wrow[2], wd = wrow[3];
            float w[16] = { wa.x, wa.y, wa.z, wa.w, wb.x, wb.y, wb.z, wb.w,
                            wc.x, wc.y, wc.z, wc.w, wd.x, wd.y, wd.z, wd.w };
#pragma unroll
            for (int i = 0; i < 16; i++) {
                acc[0][i] += w[i] * d0;
                acc[1][i] += w[i] * d1;
                acc[2][i] += w[i] * d2;
                acc[3][i] += w[i] * d3;
            }
        }
    }

#pragma unroll
    for (int i = 0; i < 16; i++) {
        int o = obase + i;
        size_t ob = (size_t)b * ((size_t)COUT * T_ * N_)
                  + (size_t)o * (T_ * N_) + (size_t)t * N_ + q0 + qb;
        out[ob]       = acc[0][i];
        out[ob + 64]  = acc[1][i];
        out[ob + 128] = acc[2][i];
        out[ob + 192] = acc[3][i];
    }
}

extern "C" void kernel_launch(void* const* d_in, const int* in_sizes, int n_in,
                              void* d_out, int out_size, void* d_ws, size_t ws_size,
                              hipStream_t stream) {
    const float* x  = (const float*)d_in[0];
    const float* La = (const float*)d_in[1];
    const float* W  = (const float*)d_in[2];
    float* out = (float*)d_out;

    const size_t n_x  = (size_t)B_ * CIN * T_ * N_;   // 33,554,432
    const size_t n_La = (size_t)B_ * N_ * N_;         //  4,194,304

    char* ws = (char*)d_ws;
    unsigned short* xb  = (unsigned short*)ws;                         // 64 MiB
    unsigned short* Lab = (unsigned short*)(ws + n_x * 2);             //  8 MiB
    unsigned short* z1b = (unsigned short*)(ws + n_x * 2 + n_La * 2);  // 64 MiB
    unsigned short* z2b = (unsigned short*)(ws + n_x * 4 + n_La * 2);  // 64 MiB
    float*          Wp  = (float*)(ws + n_x * 6 + n_La * 2);           // 48 KiB

    cvt_f32_bf16<<<(int)(n_x / 2048),  256, 0, stream>>>(x,  xb,  (int)n_x);
    cvt_f32_bf16<<<(int)(n_La / 2048), 256, 0, stream>>>(La, Lab, (int)n_La);
    pack_w<<<48, 256, 0, stream>>>(W, Wp);

    dim3 gg(N_ / BN, M_ / BM, B_);   // (4, 32, 16)
    gemm_bt<<<gg, 256, 0, stream>>>(xb,  Lab, z1b, xb, 0);
    gemm_bt<<<gg, 256, 0, stream>>>(z1b, Lab, z2b, xb, 1);

    dim3 gp(N_ / 256, T_, B_);       // (2, 64, 16)
    proj<<<gp, 256, 0, stream>>>(xb, z1b, z2b, Wp, out);
}

// Round 2
// 469.742 us; speedup vs baseline: 1.2459x; 1.2459x over previous
//
#include <hip/hip_runtime.h>
#include <hip/hip_bf16.h>

// Problem dims (fixed by reference):
//   x:  [B=16, c_in=64, T=64, N=512] fp32
//   La: [B=16, N=512, N=512] fp32
//   W:  [c_out=64, K*c_in=192] fp32
//   out:[B, 64, T, N] fp32
// Math: out[b,o,t,q] = sum_{c,k} W[o, c*3+k] * z_k[b,c,t,q]
//   z0 = x ; z1 = X @ La^T (rows ct, reduce n) ; z2 = 2*(z1 @ La^T) - x

#define B_   16
#define CIN  64
#define T_   64
#define N_   512
#define M_   4096   // CIN*T_ rows per batch
#define KDIM 512
#define COUT 64

typedef __bf16 bf16x8 __attribute__((ext_vector_type(8)));
typedef float  floatx4 __attribute__((ext_vector_type(4)));

__device__ __forceinline__ float bf2f(unsigned short u) {
    unsigned int v = ((unsigned int)u) << 16;
    return __builtin_bit_cast(float, v);
}
__device__ __forceinline__ unsigned short f2bf(float f) {
    unsigned int u = __builtin_bit_cast(unsigned int, f);
    unsigned int lsb = (u >> 16) & 1u;
    u += 0x7fffu + lsb;           // round-to-nearest-even
    return (unsigned short)(u >> 16);
}

// async global->LDS, 16B per lane; LDS dest = wave-uniform base + lane*16
#define GLOAD_LDS16(gp, lp)                                                  \
    __builtin_amdgcn_global_load_lds(                                        \
        (const __attribute__((address_space(1))) void*)(gp),                 \
        (__attribute__((address_space(3))) void*)(lp), 16, 0, 0)

// ---- K0a/K0b: fp32 -> bf16 convert, 8 elems/thread ----
__global__ __launch_bounds__(256) void cvt_f32_bf16(
    const float* __restrict__ src, unsigned short* __restrict__ dst, int n)
{
    int i = (blockIdx.x * 256 + threadIdx.x) * 8;
    if (i + 8 <= n) {
        float4 a = *(const float4*)(src + i);
        float4 b = *(const float4*)(src + i + 4);
        union { unsigned short s[8]; uint4 u; } o;
        o.s[0] = f2bf(a.x); o.s[1] = f2bf(a.y); o.s[2] = f2bf(a.z); o.s[3] = f2bf(a.w);
        o.s[4] = f2bf(b.x); o.s[5] = f2bf(b.y); o.s[6] = f2bf(b.z); o.s[7] = f2bf(b.w);
        *(uint4*)(dst + i) = o.u;
    }
}

// ---- K0c: repack W[o][c*3+k] -> Wb[o][j=k*64+c] bf16 (A-operand layout) ----
__global__ __launch_bounds__(256) void pack_w(
    const float* __restrict__ W, unsigned short* __restrict__ Wb)
{
    int idx = threadIdx.x + blockIdx.x * 256;   // idx = o*192 + j
    if (idx < 64 * 192) {
        int o = idx / 192, j = idx % 192;
        int c = j & 63, k = j >> 6;
        Wb[idx] = f2bf(W[o * 192 + c * 3 + k]);
    }
}

// ---- K1/K2: batched bf16 NT-GEMM  C[m][q] = sum_n A[m][n]*Bm[q][n] ----
// m97 pattern: unpadded LDS, global_load_lds width=16, xor chunk swizzle.
#define BM 128
#define BN 128
#define BK 32

__global__ __launch_bounds__(256) void gemm_bt(
    const unsigned short* __restrict__ A,
    const unsigned short* __restrict__ Bm,
    unsigned short* __restrict__ C,
    const unsigned short* __restrict__ X,
    int mode)
{
    int batch = blockIdx.z;
    A  += (size_t)batch * M_ * KDIM;
    Bm += (size_t)batch * N_ * KDIM;
    C  += (size_t)batch * M_ * N_;
    X  += (size_t)batch * M_ * N_;
    int m0 = blockIdx.y * BM;
    int n0 = blockIdx.x * BN;

    __shared__ __align__(16) unsigned short As[BM * BK];   // 8 KB
    __shared__ __align__(16) unsigned short Bs[BN * BK];   // 8 KB

    int tid  = threadIdx.x;
    int lane = tid & 63;
    int wave = tid >> 6;
    int wm   = (wave >> 1) * 64;
    int wn   = (wave & 1) * 64;
    int l15  = lane & 15;
    int quad = lane >> 4;

    // staging: lane l -> row (wave*16 + l>>2), dest slot l&3; source chunk
    // xor-swizzled so LDS slot s of row r holds global chunk s^(r&3).
    int r16 = lane >> 2;
    int sch = lane & 3;
    int gch = sch ^ (r16 & 3);

    const unsigned short* gA0 = A  + (size_t)(m0 + wave * 16 + r16) * KDIM + gch * 8;
    const unsigned short* gA1 = gA0 + (size_t)64 * KDIM;
    const unsigned short* gB0 = Bm + (size_t)(n0 + wave * 16 + r16) * KDIM + gch * 8;
    const unsigned short* gB1 = gB0 + (size_t)64 * KDIM;
    const unsigned short* lA0 = &As[(wave * 16) * BK];
    const unsigned short* lA1 = &As[(64 + wave * 16) * BK];
    const unsigned short* lB0 = &Bs[(wave * 16) * BK];
    const unsigned short* lB1 = &Bs[(64 + wave * 16) * BK];

    // fragment LDS addresses (loop-invariant): row rr, slot quad^(rr&3)
    const uint4* afp[4];
    const uint4* bfp[4];
    int sl = quad ^ (l15 & 3);
#pragma unroll
    for (int im = 0; im < 4; im++)
        afp[im] = (const uint4*)((const char*)As + (wm + im * 16 + l15) * (BK * 2) + sl * 16);
#pragma unroll
    for (int jn = 0; jn < 4; jn++)
        bfp[jn] = (const uint4*)((const char*)Bs + (wn + jn * 16 + l15) * (BK * 2) + sl * 16);

    floatx4 acc[4][4];
#pragma unroll
    for (int i = 0; i < 4; i++)
#pragma unroll
        for (int j = 0; j < 4; j++) acc[i][j] = (floatx4)0.0f;

    for (int k0 = 0; k0 < KDIM; k0 += BK) {
        __syncthreads();
        GLOAD_LDS16(gA0 + k0, lA0);
        GLOAD_LDS16(gA1 + k0, lA1);
        GLOAD_LDS16(gB0 + k0, lB0);
        GLOAD_LDS16(gB1 + k0, lB1);
        __syncthreads();   // drains vmcnt before barrier -> LDS ready

        bf16x8 af[4], bf[4];
#pragma unroll
        for (int im = 0; im < 4; im++) af[im] = __builtin_bit_cast(bf16x8, *afp[im]);
#pragma unroll
        for (int jn = 0; jn < 4; jn++) bf[jn] = __builtin_bit_cast(bf16x8, *bfp[jn]);
#pragma unroll
        for (int im = 0; im < 4; im++)
#pragma unroll
            for (int jn = 0; jn < 4; jn++)
                acc[im][jn] = __builtin_amdgcn_mfma_f32_16x16x32_bf16(
                    af[im], bf[jn], acc[im][jn], 0, 0, 0);
    }

    // epilogue: C/D layout col = lane&15, row = quad*4 + reg   [m89/m91]
#pragma unroll
    for (int im = 0; im < 4; im++)
#pragma unroll
        for (int jn = 0; jn < 4; jn++) {
            int c = n0 + wn + jn * 16 + l15;
#pragma unroll
            for (int r = 0; r < 4; r++) {
                int m = m0 + wm + im * 16 + quad * 4 + r;
                size_t idx = (size_t)m * N_ + c;
                float v = acc[im][jn][r];
                if (mode) v = 2.0f * v - bf2f(X[idx]);
                C[idx] = f2bf(v);
            }
        }
}

// ---- K3: projection as MFMA GEMM ----
// Per batch: C[o=64][n=tq=32768] = Wb[64][192] @ D[192][n],
// D rows j=k*64+c -> z_k row c. B-fragments need D^T[n][j]: stage 32j x 256n
// chunks transposed in LDS (pitch 40 -> 16B-aligned b128 reads, 2-way max).
#define PJ_PITCH 40

__global__ __launch_bounds__(256) void proj(
    const unsigned short* __restrict__ xb,
    const unsigned short* __restrict__ z1b,
    const unsigned short* __restrict__ z2b,
    const unsigned short* __restrict__ Wb,
    float* __restrict__ out)
{
    __shared__ __align__(16) unsigned short Ds[256 * PJ_PITCH];   // 20 KB

    int b  = blockIdx.y;
    int n0 = blockIdx.x * 256;
    int tid  = threadIdx.x;
    int lane = tid & 63;
    int wave = tid >> 6;
    int l15  = lane & 15;
    int quad = lane >> 4;

    size_t boff = (size_t)b * M_ * N_ + n0;
    const unsigned short* zp[3] = { xb + boff, z1b + boff, z2b + boff };

    // A-operand (W) fragments in registers: wave w -> o-tile [w*16, w*16+16)
    bf16x8 wf[6];
#pragma unroll
    for (int kc = 0; kc < 6; kc++)
        wf[kc] = __builtin_bit_cast(bf16x8,
            *(const uint4*)(Wb + (size_t)(wave * 16 + l15) * 192 + kc * 32 + quad * 8));

    floatx4 acc[16];
#pragma unroll
    for (int i = 0; i < 16; i++) acc[i] = (floatx4)0.0f;

    // staging mapping: row jl = tid&31 (j within 32-chunk), col group tid>>5
    int jl  = tid & 31;
    int nc0 = (tid >> 5) * 8;

    for (int kc = 0; kc < 6; kc++) {
        const unsigned short* src =
            zp[kc >> 1] + (size_t)((kc & 1) * 32 + jl) * (T_ * N_) + nc0;
        uint4 v[4];
#pragma unroll
        for (int u = 0; u < 4; u++) v[u] = *(const uint4*)(src + u * 64);

        __syncthreads();   // previous chunk's compute done before overwrite
#pragma unroll
        for (int u = 0; u < 4; u++) {
            unsigned short* d = &Ds[(size_t)(nc0 + u * 64) * PJ_PITCH + jl];
            unsigned int w0 = v[u].x, w1 = v[u].y, w2 = v[u].z, w3 = v[u].w;
            d[0 * PJ_PITCH] = (unsigned short)w0;
            d[1 * PJ_PITCH] = (unsigned short)(w0 >> 16);
            d[2 * PJ_PITCH] = (unsigned short)w1;
            d[3 * PJ_PITCH] = (unsigned short)(w1 >> 16);
            d[4 * PJ_PITCH] = (unsigned short)w2;
            d[5 * PJ_PITCH] = (unsigned short)(w2 >> 16);
            d[6 * PJ_PITCH] = (unsigned short)w3;
            d[7 * PJ_PITCH] = (unsigned short)(w3 >> 16);
        }
        __syncthreads();

#pragma unroll
        for (int nt = 0; nt < 16; nt++) {
            bf16x8 bf = __builtin_bit_cast(bf16x8,
                *(const uint4*)(&Ds[(size_t)(nt * 16 + l15) * PJ_PITCH + quad * 8]));
            acc[nt] = __builtin_amdgcn_mfma_f32_16x16x32_bf16(wf[kc], bf, acc[nt], 0, 0, 0);
        }
    }

    // epilogue: col(l15) = n, row(quad*4+r) = o within wave's 16-tile
    float* ob = out + (size_t)b * COUT * (T_ * N_);
#pragma unroll
    for (int nt = 0; nt < 16; nt++) {
        int n = n0 + nt * 16 + l15;
#pragma unroll
        for (int r = 0; r < 4; r++) {
            int o = wave * 16 + quad * 4 + r;
            ob[(size_t)o * (T_ * N_) + n] = acc[nt][r];
        }
    }
}

extern "C" void kernel_launch(void* const* d_in, const int* in_sizes, int n_in,
                              void* d_out, int out_size, void* d_ws, size_t ws_size,
                              hipStream_t stream) {
    const float* x  = (const float*)d_in[0];
    const float* La = (const float*)d_in[1];
    const float* W  = (const float*)d_in[2];
    float* out = (float*)d_out;

    const size_t n_x  = (size_t)B_ * CIN * T_ * N_;   // 33,554,432
    const size_t n_La = (size_t)B_ * N_ * N_;         //  4,194,304

    char* ws = (char*)d_ws;
    unsigned short* xb  = (unsigned short*)ws;                         // 64 MiB
    unsigned short* Lab = (unsigned short*)(ws + n_x * 2);             //  8 MiB
    unsigned short* z1b = (unsigned short*)(ws + n_x * 2 + n_La * 2);  // 64 MiB
    unsigned short* z2b = (unsigned short*)(ws + n_x * 4 + n_La * 2);  // 64 MiB
    unsigned short* Wb  = (unsigned short*)(ws + n_x * 6 + n_La * 2);  // 24 KiB

    cvt_f32_bf16<<<(int)(n_x / 2048),  256, 0, stream>>>(x,  xb,  (int)n_x);
    cvt_f32_bf16<<<(int)(n_La / 2048), 256, 0, stream>>>(La, Lab, (int)n_La);
    pack_w<<<48, 256, 0, stream>>>(W, Wb);

    dim3 gg(N_ / BN, M_ / BM, B_);   // (4, 32, 16)
    gemm_bt<<<gg, 256, 0, stream>>>(xb,  Lab, z1b, xb, 0);
    gemm_bt<<<gg, 256, 0, stream>>>(z1b, Lab, z2b, xb, 1);

    dim3 gp((T_ * N_) / 256, B_);    // (128, 16)
    proj<<<gp, 256, 0, stream>>>(xb, z1b, z2b, Wb, out);
}